// Round 7
// baseline (82.995 us; speedup 1.0000x reference)
//
#include <hip/hip_runtime.h>
#include <math.h>

#define SS 8
#define CC 16
#define HH 64
#define WW 96
#define DD 64
#define NN (HH*WW)
#define PW 100            // padded width: 2 zero cols each side
#define PH 66             // padded height: 1 zero row each side
#define PN (PH*PW)        // 6600 padded pixels per source

typedef _Float16 h2 __attribute__((ext_vector_type(2)));
struct alignas(16) H8 { h2 v[4]; };   // 8 halfs = 16 B

// Prep: transpose+convert src (S,C,H,W) -> f16 zero-padded channel-last
// (S, PH, PW, C); cur (C,H,W) -> f16 (H,W,C); folded projection matrices;
// 64 log depths; AND the depth_planes output (data-independent of the
// gather -> cheaper here as coalesced float4 stores than in cost_kernel).
__global__ __launch_bounds__(256) void prep_kernel(
    const float* __restrict__ cur, const float* __restrict__ src,
    const float* __restrict__ ext, const float* __restrict__ Ks,
    const float* __restrict__ invK, const float* __restrict__ mnp,
    const float* __restrict__ mxp,
    _Float16* __restrict__ srcT, _Float16* __restrict__ curT,
    float* __restrict__ mats, float* __restrict__ depths,
    float* __restrict__ out)
{
    int tid = blockIdx.x * 256 + threadIdx.x;
    const int srcPad = SS * PN;             // 52800
    const int t1 = srcPad + NN;             // 58944
    const int t2 = t1 + DD * NN / 4;        // + 98304 depth-plane float4 writers
    if (tid < srcPad) {
        int s = tid / PN;
        int rem = tid % PN;
        int py = rem / PW;
        int px = rem % PW;
        _Float16 v[CC] = {};                // zeros for border texels
        if (py >= 1 && py <= HH && px >= 2 && px <= WW + 1) {
            int p = (py - 1) * WW + (px - 2);
            const float* base = src + (size_t)s * CC * NN + p;
#pragma unroll
            for (int c = 0; c < CC; ++c) v[c] = (_Float16)base[c * NN];
        }
        H8* o = (H8*)(srcT + (size_t)tid * CC);
        o[0] = *(H8*)&v[0];
        o[1] = *(H8*)&v[8];
    } else if (tid < t1) {
        int p = tid - srcPad;
        const float* base = cur + p;
        _Float16 v[CC];
#pragma unroll
        for (int c = 0; c < CC; ++c) v[c] = (_Float16)base[c * NN];
        H8* o = (H8*)(curT + (size_t)p * CC);
        o[0] = *(H8*)&v[0];
        o[1] = *(H8*)&v[8];
    } else if (tid < t2) {
        // depth_planes: out[DD*NN + d*NN + n..n+3] = depth(d), coalesced float4
        int idx = tid - t1;                 // 0..98303
        int d = idx / (NN / 4);
        int n4 = idx % (NN / 4);
        float lmn = logf(mnp[0]);
        float lr  = logf(mxp[0] / mnp[0]);
        float dep = expf(lmn + lr * ((float)d * (1.0f / (DD - 1))));
        ((float4*)(out + (size_t)DD * NN + (size_t)d * NN))[n4] =
            make_float4(dep, dep, dep, dep);
    }
    if (blockIdx.x == 0) {
        if (threadIdx.x < DD) {
            float lmn = logf(mnp[0]);
            float lr  = logf(mxp[0] / mnp[0]);
            depths[threadIdx.x] = expf(lmn + lr * ((float)threadIdx.x * (1.0f / (DD - 1))));
        } else if (threadIdx.x < DD + SS) {
            int s = threadIdx.x - DD;
            float P[3][4];
            for (int i = 0; i < 3; ++i)
                for (int j = 0; j < 4; ++j) {
                    float a = 0.f;
                    for (int k = 0; k < 4; ++k)
                        a += Ks[s * 16 + i * 4 + k] * ext[s * 16 + k * 4 + j];
                    P[i][j] = a;
                }
            for (int i = 0; i < 3; ++i) {
                for (int j = 0; j < 3; ++j) {
                    float a = 0.f;
                    for (int k = 0; k < 3; ++k)
                        a += P[i][k] * invK[k * 4 + j];
                    mats[s * 12 + i * 3 + j] = a;
                }
                mats[s * 12 + 9 + i] = P[i][3];
            }
        }
    }
}

// Main: block = 8x8 pixel tile x 4 consecutive depths (one depth per wave).
// Wave-uniform skip of fully-OOB (depth, source) pairs; scalar loads for the
// per-source matrices (uniform s) and depth (readfirstlane); float-side clamps.
// Single store per thread (depth_planes handled by prep).
__global__ __launch_bounds__(256, 6) void cost_kernel(
    const _Float16* __restrict__ curT, const _Float16* __restrict__ srcT,
    const float* __restrict__ mats, const float* __restrict__ depths,
    float* __restrict__ out)
{
    int tid = threadIdx.x;
    const int TX = WW / 8;                 // 12
    const int TY = HH / 8;                 // 8
    int bx = blockIdx.x;
    int dg  = bx / (TX * TY);              // 0..15
    int rem = bx % (TX * TY);
    int tyi = rem / TX;
    int txi = rem % TX;
    int lane = tid & 63;
    int dsub = tid >> 6;                   // wave index = depth sub-index
    int d  = dg * 4 + dsub;
    int px = txi * 8 + (lane & 7);
    int py = tyi * 8 + (lane >> 3);
    int n  = py * WW + px;

    float x = (float)px + 0.5f;
    float y = (float)py + 0.5f;

    const H8* cp = (const H8*)(curT + (size_t)n * CC);
    H8 cA = cp[0], cB = cp[1];
    // d is wave-uniform; force scalar load of the depth
    float depth = depths[__builtin_amdgcn_readfirstlane(d)];

    float acc = 0.f;
#pragma unroll 2
    for (int s = 0; s < SS; ++s) {
        const float* m = &mats[s * 12];    // s loop-uniform -> s_load
        float m0 = m[0], m1 = m[1], m2 = m[2], m3 = m[3], m4 = m[4], m5 = m[5];
        float m6 = m[6], m7 = m[7], m8 = m[8], m9 = m[9], m10 = m[10], m11 = m[11];
        float qx = m0 * x + m1 * y + m2;
        float qy = m3 * x + m4 * y + m5;
        float qz = m6 * x + m7 * y + m8;
        float pz = depth * qz + m11;
        bool ok = pz > 0.f;
        float r = __builtin_amdgcn_rcpf(pz + 1e-8f);   // u = px/(z+EPS) per ref
        float u = (depth * qx + m9)  * r - 0.5f;
        float v = (depth * qy + m10) * r - 0.5f;
        // wave-uniform skip: contribution is exactly 0 when z<=0 or all 4 taps OOB
        bool contrib = ok && (u > -1.f) && (u < (float)WW) && (v > -1.f) && (v < (float)HH);
        if (__ballot(contrib) == 0ull) continue;
        // float-side clamps keep both taps of each pair inside the padded image
        // and in the zero border when OOB (v_med3_f32); !ok -> far border
        float uc = ok ? fminf(fmaxf(u, -2.0f), 96.5f) : -2.0f;
        float vc = ok ? fminf(fmaxf(v, -1.0f), 64.5f) : -1.0f;
        float x0f = floorf(uc), y0f = floorf(vc);
        float wx = uc - x0f, wy = vc - y0f;
        int x0p = (int)x0f + 2;                  // [0, 98]
        int y0p = (int)y0f + 1;                  // [0, 65]
        int y1p = min(y0p + 1, PH - 1);          // [1, 65]
        const _Float16* sbase = srcT + (size_t)s * (PN * CC);
        const H8* r0 = (const H8*)(sbase + (size_t)(y0p * PW + x0p) * CC);
        const H8* r1 = (const H8*)(sbase + (size_t)(y1p * PW + x0p) * CC);
        H8 a0 = r0[0], a1 = r0[1], a2 = r0[2], a3 = r0[3];   // row0: left|right tap
        H8 b0 = r1[0], b1 = r1[1], b2 = r1[2], b3 = r1[3];   // row1: left|right tap
        float dL0 = 0.f, dR0 = 0.f, dL1 = 0.f, dR1 = 0.f;
#pragma unroll
        for (int q = 0; q < 4; ++q) {
            dL0 = __builtin_amdgcn_fdot2(a0.v[q], cA.v[q], dL0, false);
            dL0 = __builtin_amdgcn_fdot2(a1.v[q], cB.v[q], dL0, false);
            dR0 = __builtin_amdgcn_fdot2(a2.v[q], cA.v[q], dR0, false);
            dR0 = __builtin_amdgcn_fdot2(a3.v[q], cB.v[q], dR0, false);
            dL1 = __builtin_amdgcn_fdot2(b0.v[q], cA.v[q], dL1, false);
            dL1 = __builtin_amdgcn_fdot2(b1.v[q], cB.v[q], dL1, false);
            dR1 = __builtin_amdgcn_fdot2(b2.v[q], cA.v[q], dR1, false);
            dR1 = __builtin_amdgcn_fdot2(b3.v[q], cB.v[q], dR1, false);
        }
        float d0 = dL0 + wx * (dR0 - dL0);
        float d1 = dL1 + wx * (dR1 - dL1);
        acc += d0 + wy * (d1 - d0);
    }
    out[(size_t)d * NN + n] = acc;                      // cost_volume
}

extern "C" void kernel_launch(void* const* d_in, const int* in_sizes, int n_in,
                              void* d_out, int out_size, void* d_ws, size_t ws_size,
                              hipStream_t stream) {
    const float* cur  = (const float*)d_in[0];
    const float* src  = (const float*)d_in[1];
    const float* ext  = (const float*)d_in[2];
    const float* Ks   = (const float*)d_in[3];
    const float* invK = (const float*)d_in[4];
    const float* mn   = (const float*)d_in[5];
    const float* mx   = (const float*)d_in[6];
    float* out = (float*)d_out;

    char* ws = (char*)d_ws;
    _Float16* srcT = (_Float16*)ws;                     // S*PN*C halfs ≈ 1.69 MB
    _Float16* curT = srcT + (size_t)SS * PN * CC;       // N*C halfs
    float* mats    = (float*)(curT + (size_t)NN * CC);  // 96
    float* depths  = mats + SS * 12;                    // 64

    int prepThreads = SS * PN + NN + DD * NN / 4;       // 157248
    int prepBlocks = (prepThreads + 255) / 256;         // 615
    prep_kernel<<<prepBlocks, 256, 0, stream>>>(cur, src, ext, Ks, invK, mn, mx,
                                                srcT, curT, mats, depths, out);
    cost_kernel<<<(DD / 4) * (WW / 8) * (HH / 8), 256, 0, stream>>>(curT, srcT, mats, depths, out);
}